// Round 14
// baseline (1212.760 us; speedup 1.0000x reference)
//
#include <hip/hip_runtime.h>
#include <math.h>

#define BB 256
#define NN 1023
#define FF 8
#define HH 256
#define DEPTH 9
#define LDW 832   // slice row: [h_new 256 | d+pad 64 | h_l 256 | h_r 256]

enum { EPI_SIGMUL = 1, EPI_RELU = 2, EPI_COMBINE = 3 };

typedef __bf16 bf16x8_t __attribute__((ext_vector_type(8)));
typedef float f32x4_t __attribute__((ext_vector_type(4)));

__device__ __forceinline__ void stage16(const void* g, void* l) {
    __builtin_amdgcn_global_load_lds(
        (const __attribute__((address_space(1))) void*)g,
        (__attribute__((address_space(3))) void*)l,
        16, 0, 0);
}

__device__ __forceinline__ int xcd_remap(int hw, int nwg) {
    const int xcd = hw & 7, k0 = hw >> 3;
    const int qq = nwg >> 3, rr = nwg & 7;
    return (xcd < rr ? xcd * (qq + 1) : rr * (qq + 1) + (xcd - rr) * qq) + k0;
}

// ======== 256x256 tile, BK=64, 16 waves, counted vmcnt (r13 K-loop) =========
// Folded-K GEMMs. SIGMUL: A=slice+256 (K=576) -> rh. COMBINE: A=slice (K=832)
// -> children written into parent slice slots. u read from ubuf in epilogues.
template <int EPI>
__global__ __launch_bounds__(1024, 4) void gemm256w(
    const __bf16* __restrict__ A, int lda,
    const __bf16* __restrict__ W,       // Nc x K row-major (folded)
    const float* __restrict__ bias,
    const __bf16* __restrict__ slice,   // full 832-col slice (epilogue)
    const __bf16* __restrict__ ubuf,    // chunk-local u (epilogue)
    void* __restrict__ Cout, int ldc,
    int r0c, int K)
{
    __shared__ __bf16 lds[2][2][256 * 64];  // 128 KiB
    const int tid = threadIdx.x;
    const int lane = tid & 63;
    const int w = tid >> 6;            // 0..15
    const int wr = w >> 2, wc = w & 3; // per-wave C = 64x64

    const int nwg = gridDim.x * gridDim.y;
    const int hw = blockIdx.y * gridDim.x + blockIdx.x;
    const int wg = xcd_remap(hw, nwg);
    const int bm0 = (wg / gridDim.x) * 256;
    const int bn0 = (wg % gridDim.x) * 256;

    const int srow = tid >> 3;                       // 0..127
    const int scolz = ((tid & 7) ^ (srow & 7)) * 8;  // inv-swizzled col

    f32x4_t acc[4][4];
#pragma unroll
    for (int i = 0; i < 4; ++i)
#pragma unroll
        for (int j = 0; j < 4; ++j) acc[i][j] = (f32x4_t){0.f, 0.f, 0.f, 0.f};

    const int rA = lane & 15;
    const int klane = (lane >> 4) * 8;
    const int rxor = (lane & 7) * 8;
    const int NT = K >> 6;

#define STAGE_T(t, buf)                                                        \
    do {                                                                       \
        const int kk_ = (t) << 6;                                              \
        stage16(A + (size_t)(bm0 + srow) * lda + kk_ + scolz,                  \
                &lds[buf][0][w * 512]);                                        \
        stage16(A + (size_t)(bm0 + 128 + srow) * lda + kk_ + scolz,            \
                &lds[buf][0][8192 + w * 512]);                                 \
        stage16(W + (size_t)(bn0 + srow) * K + kk_ + scolz,                    \
                &lds[buf][1][w * 512]);                                        \
        stage16(W + (size_t)(bn0 + 128 + srow) * K + kk_ + scolz,              \
                &lds[buf][1][8192 + w * 512]);                                 \
    } while (0)
#define LDA_F(As_, i, ks) \
    (*(const bf16x8_t*)&(As_)[(wr * 64 + (i) * 16 + rA) * 64 + (((ks) * 32 + klane) ^ rxor)])
#define LDB_F(Bs_, j, ks) \
    (*(const bf16x8_t*)&(Bs_)[(wc * 64 + (j) * 16 + rA) * 64 + (((ks) * 32 + klane) ^ rxor)])

    STAGE_T(0, 0);
    STAGE_T(1, 1);
    asm volatile("s_waitcnt vmcnt(4)" ::: "memory");
    __builtin_amdgcn_s_barrier();

    for (int t = 0; t < NT; ++t) {
        const int cur = t & 1;
        const __bf16* As = lds[cur][0];
        const __bf16* Bs = lds[cur][1];
        bf16x8_t af[4], bf[4];

#pragma unroll
        for (int j = 0; j < 4; ++j) bf[j] = LDB_F(Bs, j, 0);
#pragma unroll
        for (int i = 0; i < 4; ++i) af[i] = LDA_F(As, i, 0);
#pragma unroll
        for (int i = 0; i < 4; ++i)
#pragma unroll
            for (int j = 0; j < 4; ++j)
                acc[i][j] = __builtin_amdgcn_mfma_f32_16x16x32_bf16(
                    af[i], bf[j], acc[i][j], 0, 0, 0);
#pragma unroll
        for (int j = 0; j < 4; ++j) bf[j] = LDB_F(Bs, j, 1);
#pragma unroll
        for (int i = 0; i < 4; ++i) af[i] = LDA_F(As, i, 1);
#pragma unroll
        for (int i = 0; i < 2; ++i)
#pragma unroll
            for (int j = 0; j < 4; ++j)
                acc[i][j] = __builtin_amdgcn_mfma_f32_16x16x32_bf16(
                    af[i], bf[j], acc[i][j], 0, 0, 0);

        asm volatile("s_waitcnt lgkmcnt(0)" ::: "memory");
        __builtin_amdgcn_s_barrier();
        if (t + 2 < NT) STAGE_T(t + 2, cur);

        __builtin_amdgcn_s_setprio(1);
#pragma unroll
        for (int i = 2; i < 4; ++i)
#pragma unroll
            for (int j = 0; j < 4; ++j)
                acc[i][j] = __builtin_amdgcn_mfma_f32_16x16x32_bf16(
                    af[i], bf[j], acc[i][j], 0, 0, 0);
        __builtin_amdgcn_s_setprio(0);

        if (t + 1 < NT) {
            if (t + 2 < NT) {
                asm volatile("s_waitcnt vmcnt(4)" ::: "memory");
            } else {
                asm volatile("s_waitcnt vmcnt(0)" ::: "memory");
            }
            __builtin_amdgcn_s_barrier();
        }
    }
#undef STAGE_T
#undef LDA_F
#undef LDB_F

    const int hi = lane >> 4;
    const int r = lane & 15;

    if (EPI == EPI_COMBINE) {
        // h -> parent slice slots via LDS bounce panel, coalesced.
        __bf16* pan = &lds[0][0][0];  // [256][72]
        const int g0 = bn0 >> 2;
        float bz4[4];
#pragma unroll
        for (int g = 0; g < 4; ++g) bz4[g] = bias[bn0 + wc * 64 + g * 16 + r];
        const int G = g0 + wc * 16 + r;
#pragma unroll
        for (int i = 0; i < 4; ++i) {
#pragma unroll
            for (int reg = 0; reg < 4; ++reg) {
                const int lr = wr * 64 + i * 16 + hi * 4 + reg;
                const int gr = bm0 + lr;
                float z0 = acc[i][0][reg] + bz4[0];
                float z1 = acc[i][1][reg] + bz4[1];
                float z2 = acc[i][2][reg] + bz4[2];
                float z3 = acc[i][3][reg] + bz4[3];
                float mx = fmaxf(fmaxf(z0, z1), fmaxf(z2, z3));
                float e0 = __expf(z0 - mx), e1 = __expf(z1 - mx);
                float e2 = __expf(z2 - mx), e3 = __expf(z3 - mx);
                const __bf16* srow_ = slice + (size_t)gr * LDW;
                float a0v = (float)srow_[G];
                float a1v = (float)ubuf[(size_t)gr * HH + G];
                float a2v = (float)srow_[320 + G];
                float a3v = (float)srow_[576 + G];
                float hv = (e0 * a0v + e1 * a1v + e2 * a2v + e3 * a3v) /
                           (e0 + e1 + e2 + e3);
                pan[lr * 72 + wc * 16 + r] = (__bf16)hv;
            }
        }
        __syncthreads();
        const int cbase = r0c + bm0;
#pragma unroll
        for (int it = 0; it < 2; ++it) {
            const int unit = it * 1024 + tid;
            const int row = unit >> 3;
            const int c8 = (unit & 7) * 8;
            const int crow = cbase + row;
            bf16x8_t vv = *(const bf16x8_t*)&pan[row * 72 + c8];
            *(bf16x8_t*)((__bf16*)Cout + (size_t)(crow >> 1) * LDW + 320 +
                         (crow & 1) * 256 + g0 + c8) = vv;
        }
    } else {  // EPI_SIGMUL
        __bf16* pan = &lds[0][0][0];  // [256][256]
        float bv[4];
#pragma unroll
        for (int j = 0; j < 4; ++j) bv[j] = bias[bn0 + wc * 64 + j * 16 + r];
#pragma unroll
        for (int j = 0; j < 4; ++j) {
            const int lc = wc * 64 + j * 16 + r;
            const int gc = bn0 + lc;
#pragma unroll
            for (int i = 0; i < 4; ++i) {
#pragma unroll
                for (int reg = 0; reg < 4; ++reg) {
                    const int lr = wr * 64 + i * 16 + hi * 4 + reg;
                    const int gr = bm0 + lr;
                    float v = acc[i][j][reg] + bv[j];
                    float s = 1.0f / (1.0f + __expf(-v));
                    float a = (gc < 256)
                                  ? (float)ubuf[(size_t)gr * HH + gc]
                                  : (float)slice[(size_t)gr * LDW + 64 + gc];
                    pan[lr * 256 + lc] = (__bf16)(s * a);
                }
            }
        }
        __syncthreads();
#pragma unroll
        for (int it = 0; it < 8; ++it) {
            const int unit = it * 1024 + tid;
            const int row = unit >> 5;
            const int c8 = (unit & 31) * 8;
            bf16x8_t vv = *(const bf16x8_t*)&pan[row * 256 + c8];
            *(bf16x8_t*)((__bf16*)Cout + (size_t)(bm0 + row) * ldc + bn0 + c8) = vv;
        }
    }
}

// ---------------- 128x128-tile kernel (Wh + small levels) -------------------
template <int EPI>
__global__ __launch_bounds__(256) void gemm_mfma(
    const __bf16* __restrict__ A, int lda,
    const __bf16* __restrict__ W,
    const float* __restrict__ bias,
    const __bf16* __restrict__ slice,
    const __bf16* __restrict__ ubuf,
    void* __restrict__ Cout, int ldc,
    int r0c, int topar, int K)
{
    __shared__ __bf16 As[128 * 32];
    __shared__ __bf16 Bs[128 * 32];
    const int tid = threadIdx.x;
    const int lane = tid & 63;
    const int w = tid >> 6;
    const int wr = w >> 1, wc = w & 1;

    const int nwg = gridDim.x * gridDim.y;
    const int hw = blockIdx.y * gridDim.x + blockIdx.x;
    const int wg = xcd_remap(hw, nwg);
    const int bm0 = (wg / gridDim.x) * 128;
    const int bn0 = (wg % gridDim.x) * 128;

    const int srow = lane >> 2;
    const int scol = (lane & 3) * 8;

    f32x4_t acc[4][4];
#pragma unroll
    for (int i = 0; i < 4; ++i)
#pragma unroll
        for (int j = 0; j < 4; ++j) acc[i][j] = (f32x4_t){0.f, 0.f, 0.f, 0.f};

    const int rA = lane & 15;
    const int kslot = (lane >> 4) * 8;

    for (int kk = 0; kk < K; kk += 32) {
        stage16(A + (size_t)(bm0 + w * 16 + srow) * lda + kk + scol,
                &As[(w * 16) * 32]);
        stage16(A + (size_t)(bm0 + 64 + w * 16 + srow) * lda + kk + scol,
                &As[(64 + w * 16) * 32]);
        stage16(W + (size_t)(bn0 + w * 16 + srow) * K + kk + scol,
                &Bs[(w * 16) * 32]);
        stage16(W + (size_t)(bn0 + 64 + w * 16 + srow) * K + kk + scol,
                &Bs[(64 + w * 16) * 32]);
        __syncthreads();

        bf16x8_t af[4], bfr[4];
#pragma unroll
        for (int i = 0; i < 4; ++i)
            af[i] = *(const bf16x8_t*)&As[(wr * 64 + i * 16 + rA) * 32 + kslot];
#pragma unroll
        for (int j = 0; j < 4; ++j)
            bfr[j] = *(const bf16x8_t*)&Bs[(wc * 64 + j * 16 + rA) * 32 + kslot];
#pragma unroll
        for (int i = 0; i < 4; ++i)
#pragma unroll
            for (int j = 0; j < 4; ++j)
                acc[i][j] = __builtin_amdgcn_mfma_f32_16x16x32_bf16(
                    af[i], bfr[j], acc[i][j], 0, 0, 0);
        __syncthreads();
    }

    const int r = lane & 15;
    if (EPI == EPI_COMBINE) {
        const int G = ((bn0 + wc * 64) >> 2) + r;
        float bz4[4];
#pragma unroll
        for (int g = 0; g < 4; ++g) bz4[g] = bias[bn0 + wc * 64 + g * 16 + r];
#pragma unroll
        for (int i = 0; i < 4; ++i) {
#pragma unroll
            for (int reg = 0; reg < 4; ++reg) {
                const int gr = bm0 + wr * 64 + i * 16 + (lane >> 4) * 4 + reg;
                float z0 = acc[i][0][reg] + bz4[0];
                float z1 = acc[i][1][reg] + bz4[1];
                float z2 = acc[i][2][reg] + bz4[2];
                float z3 = acc[i][3][reg] + bz4[3];
                float mx = fmaxf(fmaxf(z0, z1), fmaxf(z2, z3));
                float e0 = __expf(z0 - mx), e1 = __expf(z1 - mx);
                float e2 = __expf(z2 - mx), e3 = __expf(z3 - mx);
                const __bf16* srow_ = slice + (size_t)gr * LDW;
                float hv = (e0 * (float)srow_[G] +
                            e1 * (float)ubuf[(size_t)gr * HH + G] +
                            e2 * (float)srow_[320 + G] +
                            e3 * (float)srow_[576 + G]) /
                           (e0 + e1 + e2 + e3);
                if (topar) {
                    const int crow = r0c + gr;
                    ((__bf16*)Cout)[(size_t)(crow >> 1) * LDW + 320 +
                                    (crow & 1) * 256 + G] = (__bf16)hv;
                } else {
                    ((__bf16*)Cout)[(size_t)gr * ldc + G] = (__bf16)hv;
                }
            }
        }
    } else {
#pragma unroll
        for (int j = 0; j < 4; ++j) {
            const int gc = bn0 + wc * 64 + j * 16 + r;
            const float bv = bias[gc];
#pragma unroll
            for (int i = 0; i < 4; ++i) {
#pragma unroll
                for (int reg = 0; reg < 4; ++reg) {
                    const int gr = bm0 + wr * 64 + i * 16 + (lane >> 4) * 4 + reg;
                    float v = acc[i][j][reg] + bv;
                    if (EPI == EPI_SIGMUL) {
                        float s = 1.0f / (1.0f + __expf(-v));
                        float a = (gc < 256)
                                      ? (float)ubuf[(size_t)gr * HH + gc]
                                      : (float)slice[(size_t)gr * LDW + 64 + gc];
                        ((__bf16*)Cout)[(size_t)gr * ldc + gc] = (__bf16)(s * a);
                    } else {  // RELU
                        v = fmaxf(v, 0.0f);
                        ((__bf16*)Cout)[(size_t)gr * ldc + gc] = (__bf16)v;
                    }
                }
            }
        }
    }
}

// Wh -> bf16.
__global__ __launch_bounds__(256) void convert_wh(
    const float* __restrict__ Wh, __bf16* __restrict__ Whb)
{
    const int NH2 = 256 * 768;
    for (int i = blockIdx.x * 256 + threadIdx.x; i < NH2; i += gridDim.x * 256)
        Whb[i] = (__bf16)Wh[i];
}

// Wr' = [Wr_u*Wu (8) | 0 (56) | Wr_l | Wr_r], br' = br + Wr_u*bu
__global__ __launch_bounds__(256) void fold_wr(
    const float* __restrict__ Wr, const float* __restrict__ Wu,
    const float* __restrict__ bu, const float* __restrict__ br,
    __bf16* __restrict__ Wrp, float* __restrict__ brp)
{
    const int j = blockIdx.x;
    const int c = threadIdx.x;
    __shared__ float red[256];
    const float wjc = Wr[(size_t)j * 768 + c];
    red[c] = wjc * bu[c];
    __syncthreads();
    for (int s = 128; s > 0; s >>= 1) { if (c < s) red[c] += red[c + s]; __syncthreads(); }
    if (c == 0) brp[j] = br[j] + red[0];
    for (int f = 0; f < 8; ++f) {
        __syncthreads();
        red[c] = wjc * Wu[c * 8 + f];
        __syncthreads();
        for (int s = 128; s > 0; s >>= 1) { if (c < s) red[c] += red[c + s]; __syncthreads(); }
        if (c == 0) Wrp[(size_t)j * 576 + f] = (__bf16)red[0];
    }
    if (c >= 8 && c < 64) Wrp[(size_t)j * 576 + c] = (__bf16)0.0f;
    Wrp[(size_t)j * 576 + 64 + c]  = (__bf16)Wr[(size_t)j * 768 + 256 + c];
    Wrp[(size_t)j * 576 + 320 + c] = (__bf16)Wr[(size_t)j * 768 + 512 + c];
}

// Wz' (row-permuted p->o) = [Wz_hnew | Wz_u*Wu (8) | 0 (56) | Wz_l | Wz_r]
__global__ __launch_bounds__(256) void fold_wz(
    const float* __restrict__ Wz, const float* __restrict__ Wu,
    const float* __restrict__ bu, const float* __restrict__ bz,
    __bf16* __restrict__ Wzp, float* __restrict__ bzpf)
{
    const int p = blockIdx.x;
    const int c = threadIdx.x;
    const int o = ((p >> 4) & 3) * 256 + (p >> 6) * 16 + (p & 15);
    __shared__ float red[256];
    const float wuc = Wz[(size_t)o * 1024 + 256 + c];
    red[c] = wuc * bu[c];
    __syncthreads();
    for (int s = 128; s > 0; s >>= 1) { if (c < s) red[c] += red[c + s]; __syncthreads(); }
    if (c == 0) bzpf[p] = bz[o] + red[0];
    for (int f = 0; f < 8; ++f) {
        __syncthreads();
        red[c] = wuc * Wu[c * 8 + f];
        __syncthreads();
        for (int s = 128; s > 0; s >>= 1) { if (c < s) red[c] += red[c + s]; __syncthreads(); }
        if (c == 0) Wzp[(size_t)p * 832 + 256 + f] = (__bf16)red[0];
    }
    if (c >= 8 && c < 64) Wzp[(size_t)p * 832 + 256 + c] = (__bf16)0.0f;
    Wzp[(size_t)p * 832 + c]       = (__bf16)Wz[(size_t)o * 1024 + c];
    Wzp[(size_t)p * 832 + 320 + c] = (__bf16)Wz[(size_t)o * 1024 + 512 + c];
    Wzp[(size_t)p * 832 + 576 + c] = (__bf16)Wz[(size_t)o * 1024 + 768 + c];
}

// l==8: slice rows <- [dpad | h_leaf_l | h_leaf_r]; ubuf <- u(parent).
__global__ __launch_bounds__(256) void build_leaf(
    const float* __restrict__ data, const float* __restrict__ Wu,
    const float* __restrict__ bu, __bf16* __restrict__ slice,
    __bf16* __restrict__ ubuf, int r0)
{
    const int blk = xcd_remap(blockIdx.x, gridDim.x);
    const int row = blk * 8 + (threadIdx.x >> 5);
    const int lc = threadIdx.x & 31;
    const int c0 = lc * 8;
    const int i = r0 + row;
    const int b = i >> 8;
    const int m = i & 255;

    float wv[8][8];
#pragma unroll
    for (int cc = 0; cc < 8; ++cc) {
        float4 w0 = *(const float4*)&Wu[(c0 + cc) * 8];
        float4 w1 = *(const float4*)&Wu[(c0 + cc) * 8 + 4];
        wv[cc][0] = w0.x; wv[cc][1] = w0.y; wv[cc][2] = w0.z; wv[cc][3] = w0.w;
        wv[cc][4] = w1.x; wv[cc][5] = w1.y; wv[cc][6] = w1.z; wv[cc][7] = w1.w;
    }
    float buv[8];
#pragma unroll
    for (int cc = 0; cc < 8; ++cc) buv[cc] = bu[c0 + cc];

    __bf16* rowp = slice + (size_t)row * LDW;
    const float* dpar = data + ((size_t)b * NN + 255 + m) * FF;
    {
        float4 d0 = *(const float4*)dpar, d1 = *(const float4*)(dpar + 4);
        float dv[8] = {d0.x, d0.y, d0.z, d0.w, d1.x, d1.y, d1.z, d1.w};
        bf16x8_t o;
#pragma unroll
        for (int cc = 0; cc < 8; ++cc) {
            float acc = buv[cc];
#pragma unroll
            for (int f = 0; f < 8; ++f) acc += dv[f] * wv[cc][f];
            o[cc] = (__bf16)acc;
        }
        *(bf16x8_t*)&ubuf[(size_t)row * HH + c0] = o;
        // dpad: first 8 lanes-of-row write 8 cols each (d then zeros)
        if (lc < 8) {
            bf16x8_t dp;
#pragma unroll
            for (int cc = 0; cc < 8; ++cc)
                dp[cc] = (lc == 0) ? (__bf16)dv[cc] : (__bf16)0.0f;
            *(bf16x8_t*)&rowp[256 + lc * 8] = dp;
        }
    }
    const float* dl = data + ((size_t)b * NN + 511 + 2 * m) * FF;
#pragma unroll
    for (int side = 0; side < 2; ++side) {
        const float* dp = dl + side * FF;
        float4 d0 = *(const float4*)dp, d1 = *(const float4*)(dp + 4);
        float dv[8] = {d0.x, d0.y, d0.z, d0.w, d1.x, d1.y, d1.z, d1.w};
        bf16x8_t o;
#pragma unroll
        for (int cc = 0; cc < 8; ++cc) {
            float acc = buv[cc];
#pragma unroll
            for (int f = 0; f < 8; ++f) acc += dv[f] * wv[cc][f];
            o[cc] = (__bf16)acc;
        }
        *(bf16x8_t*)&rowp[320 + side * 256 + c0] = o;
    }
}

// l<8: slice dpad + ubuf u. h_l/h_r already written by child COMBINE.
__global__ __launch_bounds__(256) void build_u(
    const float* __restrict__ data, const float* __restrict__ Wu,
    const float* __restrict__ bu, __bf16* __restrict__ slice,
    __bf16* __restrict__ ubuf, int l, int r0)
{
    const int n = 1 << l;
    const int blk = xcd_remap(blockIdx.x, gridDim.x);
    const int row = blk * 8 + (threadIdx.x >> 5);
    const int lc = threadIdx.x & 31;
    const int c0 = lc * 8;
    const int i = r0 + row;
    const int b = i >> l;
    const int m = i & (n - 1);

    float wv[8][8];
#pragma unroll
    for (int cc = 0; cc < 8; ++cc) {
        float4 w0 = *(const float4*)&Wu[(c0 + cc) * 8];
        float4 w1 = *(const float4*)&Wu[(c0 + cc) * 8 + 4];
        wv[cc][0] = w0.x; wv[cc][1] = w0.y; wv[cc][2] = w0.z; wv[cc][3] = w0.w;
        wv[cc][4] = w1.x; wv[cc][5] = w1.y; wv[cc][6] = w1.z; wv[cc][7] = w1.w;
    }
    const float* dp = data + ((size_t)b * NN + (n - 1) + m) * FF;
    float4 d0 = *(const float4*)dp, d1 = *(const float4*)(dp + 4);
    float dv[8] = {d0.x, d0.y, d0.z, d0.w, d1.x, d1.y, d1.z, d1.w};
    bf16x8_t o;
#pragma unroll
    for (int cc = 0; cc < 8; ++cc) {
        float acc = bu[c0 + cc];
#pragma unroll
        for (int f = 0; f < 8; ++f) acc += dv[f] * wv[cc][f];
        o[cc] = (__bf16)acc;
    }
    *(bf16x8_t*)&ubuf[(size_t)row * HH + c0] = o;
    if (lc < 8) {
        bf16x8_t dpd;
#pragma unroll
        for (int cc = 0; cc < 8; ++cc)
            dpd[cc] = (lc == 0) ? (__bf16)dv[cc] : (__bf16)0.0f;
        *(bf16x8_t*)&slice[(size_t)row * LDW + 256 + lc * 8] = dpd;
    }
}

__global__ __launch_bounds__(256) void final_kernel(
    const __bf16* __restrict__ hfin, const float* __restrict__ Wp,
    const float* __restrict__ bp, float* __restrict__ out)
{
    const int b = blockIdx.x;
    const int t = threadIdx.x;
    __shared__ float red[256];
    red[t] = (float)hfin[(size_t)b * HH + t] * Wp[t];
    __syncthreads();
    for (int s = 128; s > 0; s >>= 1) {
        if (t < s) red[t] += red[t + s];
        __syncthreads();
    }
    if (t == 0) out[b] = red[0] + bp[0];
}

extern "C" void kernel_launch(void* const* d_in, const int* in_sizes, int n_in,
                              void* d_out, int out_size, void* d_ws, size_t ws_size,
                              hipStream_t stream)
{
    const float* data = (const float*)d_in[0];
    const float* Wu = (const float*)d_in[1];
    const float* bu = (const float*)d_in[2];
    const float* Wr = (const float*)d_in[3];
    const float* br = (const float*)d_in[4];
    const float* Wh = (const float*)d_in[5];
    const float* bh = (const float*)d_in[6];
    const float* Wz = (const float*)d_in[7];
    const float* bz = (const float*)d_in[8];
    const float* Wp = (const float*)d_in[9];
    const float* bp = (const float*)d_in[10];
    float* out = (float*)d_out;

    const size_t CAP = 16384;
    char* w = (char*)d_ws;
    __bf16* hhhuA = (__bf16*)w; w += (size_t)65536 * LDW * 2;  // 109 MB (l even)
    __bf16* hhhuB = (__bf16*)w; w += (size_t)32768 * LDW * 2;  // 54.5 MB (l odd)
    __bf16* rh = (__bf16*)w;    w += CAP * 768 * 2;            // 25.2 MB
    __bf16* ubuf = (__bf16*)w;  w += CAP * HH * 2;             // 8.4 MB
    __bf16* hRoot = (__bf16*)w; w += (size_t)256 * 256 * 2;
    __bf16* Whb = (__bf16*)w;   w += (size_t)256 * 768 * 2;
    __bf16* Wrp = (__bf16*)w;   w += (size_t)768 * 576 * 2;
    float* brp = (float*)w;     w += 768 * 4;
    __bf16* Wzp = (__bf16*)w;   w += (size_t)1024 * 832 * 2;
    float* bzpf = (float*)w;    w += 1024 * 4;

    convert_wh<<<768, 256, 0, stream>>>(Wh, Whb);
    fold_wr<<<768, 256, 0, stream>>>(Wr, Wu, bu, br, Wrp, brp);
    fold_wz<<<1024, 256, 0, stream>>>(Wz, Wu, bu, bz, Wzp, bzpf);

    for (int l = DEPTH - 1; l >= 0; --l) {
        const size_t M = (size_t)BB << l;
        __bf16* cur = (l & 1) ? hhhuB : hhhuA;
        __bf16* par = (l == 0) ? hRoot : ((l & 1) ? hhhuA : hhhuB);
        const int topar = (l > 0);
        for (size_t r0 = 0; r0 < M; r0 += CAP) {
            const int R = (int)((M - r0 < CAP) ? (M - r0) : CAP);
            __bf16* slice = cur + (size_t)r0 * LDW;
            if (l == 8)
                build_leaf<<<R / 8, 256, 0, stream>>>(data, Wu, bu, slice, ubuf, (int)r0);
            else
                build_u<<<R / 8, 256, 0, stream>>>(data, Wu, bu, slice, ubuf, l, (int)r0);
            if (R >= 16384) {
                gemm256w<EPI_SIGMUL><<<dim3(3, R / 256), 1024, 0, stream>>>(
                    slice + 256, LDW, Wrp, brp, slice, ubuf, rh, 768, 0, 576);
            } else {
                gemm_mfma<EPI_SIGMUL><<<dim3(6, R / 128), 256, 0, stream>>>(
                    slice + 256, LDW, Wrp, brp, slice, ubuf, rh, 768, 0, 0, 576);
            }
            gemm_mfma<EPI_RELU><<<dim3(2, R / 128), 256, 0, stream>>>(
                rh, 768, Whb, bh, nullptr, nullptr, slice, LDW, 0, 0, 768);
            if (R >= 16384) {
                gemm256w<EPI_COMBINE><<<dim3(4, R / 256), 1024, 0, stream>>>(
                    slice, LDW, Wzp, bzpf, slice, ubuf, par, HH, (int)r0, 832);
            } else {
                gemm_mfma<EPI_COMBINE><<<dim3(8, R / 128), 256, 0, stream>>>(
                    slice, LDW, Wzp, bzpf, slice, ubuf, par, HH, (int)r0, topar, 832);
            }
        }
    }
    final_kernel<<<BB, 256, 0, stream>>>(hRoot, Wp, bp, out);
}

// Round 15
// 1175.292 us; speedup vs baseline: 1.0319x; 1.0319x over previous
//
#include <hip/hip_runtime.h>
#include <math.h>

#define BB 256
#define NN 1023
#define FF 8
#define HH 256
#define DEPTH 9

enum { EPI_SIGMUL = 1, EPI_RELU = 2, EPI_COMBINE = 3 };

typedef __bf16 bf16x8_t __attribute__((ext_vector_type(8)));
typedef float f32x4_t __attribute__((ext_vector_type(4)));

__device__ __forceinline__ void stage16(const void* g, void* l) {
    __builtin_amdgcn_global_load_lds(
        (const __attribute__((address_space(1))) void*)g,
        (__attribute__((address_space(3))) void*)l,
        16, 0, 0);
}

__device__ __forceinline__ int xcd_remap(int hw, int nwg) {
    const int xcd = hw & 7, k0 = hw >> 3;
    const int qq = nwg >> 3, rr = nwg & 7;
    return (xcd < rr ? xcd * (qq + 1) : rr * (qq + 1) + (xcd - rr) * qq) + k0;
}

// Fused u-writer: compute u = Wu*d + bu for parent rows [pbase, pbase+PR)
// and store into parent slice u-slot (cols 256..512). One writer block per
// parent range (gated on bn0==0 by caller). THREADS = block size.
template <int THREADS, int PR>
__device__ __forceinline__ void write_parent_u(
    const float* __restrict__ data, const float* __restrict__ Wu,
    const float* __restrict__ bu, __bf16* __restrict__ parbase,
    int pbase, int lpar, int tid)
{
    const int npar = 1 << lpar;
    const int UNITS = PR * 32;  // 8 cols per unit
#pragma unroll
    for (int pass = 0; pass < UNITS / THREADS; ++pass) {
        const int idx = pass * THREADS + tid;
        const int prow = pbase + (idx >> 5);
        const int c0 = (idx & 31) * 8;
        const int b = prow >> lpar;
        const int m = prow & (npar - 1);
        const float* dp = data + ((size_t)b * NN + (npar - 1) + m) * FF;
        float4 d0 = *(const float4*)dp, d1 = *(const float4*)(dp + 4);
        float dv[8] = {d0.x, d0.y, d0.z, d0.w, d1.x, d1.y, d1.z, d1.w};
        bf16x8_t o;
#pragma unroll
        for (int cc = 0; cc < 8; ++cc) {
            float acc2 = bu[c0 + cc];
            const float* wp = Wu + (c0 + cc) * 8;
#pragma unroll
            for (int f = 0; f < 8; ++f) acc2 += dv[f] * wp[f];
            o[cc] = (__bf16)acc2;
        }
        *(bf16x8_t*)&parbase[(size_t)prow * 1024 + 256 + c0] = o;
    }
}

// ======== 256x256 tile, BK=64, 16 waves (64x64 C each), counted vmcnt =======
// r13 K-loop. COMBINE epilogue writes children into parent hhhu slots via the
// dead-LDS bounce panel AND (bn0==0 blocks) computes the parent rows' u slot.
template <int EPI>
__global__ __launch_bounds__(1024, 4) void gemm256w(
    const __bf16* __restrict__ A, int lda,
    const __bf16* __restrict__ W,       // Nc x K row-major
    const float* __restrict__ bias,
    const __bf16* __restrict__ aux, int ldaux,
    void* __restrict__ Cout, int ldc,
    int r0c,
    const float* __restrict__ dataF, const float* __restrict__ WuF,
    const float* __restrict__ buF, int lev,
    int K)
{
    __shared__ __bf16 lds[2][2][256 * 64];  // 128 KiB
    const int tid = threadIdx.x;
    const int lane = tid & 63;
    const int w = tid >> 6;            // 0..15
    const int wr = w >> 2, wc = w & 3; // per-wave C = 64x64

    const int nwg = gridDim.x * gridDim.y;
    const int hw = blockIdx.y * gridDim.x + blockIdx.x;
    const int wg = xcd_remap(hw, nwg);
    const int bm0 = (wg / gridDim.x) * 256;
    const int bn0 = (wg % gridDim.x) * 256;

    const int srow = tid >> 3;                       // 0..127
    const int scolz = ((tid & 7) ^ (srow & 7)) * 8;  // inv-swizzled col

    f32x4_t acc[4][4];
#pragma unroll
    for (int i = 0; i < 4; ++i)
#pragma unroll
        for (int j = 0; j < 4; ++j) acc[i][j] = (f32x4_t){0.f, 0.f, 0.f, 0.f};

    const int rA = lane & 15;
    const int klane = (lane >> 4) * 8;
    const int rxor = (lane & 7) * 8;
    const int NT = K >> 6;

#define STAGE_T(t, buf)                                                        \
    do {                                                                       \
        const int kk_ = (t) << 6;                                              \
        stage16(A + (size_t)(bm0 + srow) * lda + kk_ + scolz,                  \
                &lds[buf][0][w * 512]);                                        \
        stage16(A + (size_t)(bm0 + 128 + srow) * lda + kk_ + scolz,            \
                &lds[buf][0][8192 + w * 512]);                                 \
        stage16(W + (size_t)(bn0 + srow) * K + kk_ + scolz,                    \
                &lds[buf][1][w * 512]);                                        \
        stage16(W + (size_t)(bn0 + 128 + srow) * K + kk_ + scolz,              \
                &lds[buf][1][8192 + w * 512]);                                 \
    } while (0)
#define LDA_F(As_, i, ks) \
    (*(const bf16x8_t*)&(As_)[(wr * 64 + (i) * 16 + rA) * 64 + (((ks) * 32 + klane) ^ rxor)])
#define LDB_F(Bs_, j, ks) \
    (*(const bf16x8_t*)&(Bs_)[(wc * 64 + (j) * 16 + rA) * 64 + (((ks) * 32 + klane) ^ rxor)])

    STAGE_T(0, 0);
    STAGE_T(1, 1);
    asm volatile("s_waitcnt vmcnt(4)" ::: "memory");
    __builtin_amdgcn_s_barrier();

    for (int t = 0; t < NT; ++t) {
        const int cur = t & 1;
        const __bf16* As = lds[cur][0];
        const __bf16* Bs = lds[cur][1];
        bf16x8_t af[4], bf[4];

#pragma unroll
        for (int j = 0; j < 4; ++j) bf[j] = LDB_F(Bs, j, 0);
#pragma unroll
        for (int i = 0; i < 4; ++i) af[i] = LDA_F(As, i, 0);
#pragma unroll
        for (int i = 0; i < 4; ++i)
#pragma unroll
            for (int j = 0; j < 4; ++j)
                acc[i][j] = __builtin_amdgcn_mfma_f32_16x16x32_bf16(
                    af[i], bf[j], acc[i][j], 0, 0, 0);
#pragma unroll
        for (int j = 0; j < 4; ++j) bf[j] = LDB_F(Bs, j, 1);
#pragma unroll
        for (int i = 0; i < 4; ++i) af[i] = LDA_F(As, i, 1);
#pragma unroll
        for (int i = 0; i < 2; ++i)
#pragma unroll
            for (int j = 0; j < 4; ++j)
                acc[i][j] = __builtin_amdgcn_mfma_f32_16x16x32_bf16(
                    af[i], bf[j], acc[i][j], 0, 0, 0);

        asm volatile("s_waitcnt lgkmcnt(0)" ::: "memory");
        __builtin_amdgcn_s_barrier();
        if (t + 2 < NT) STAGE_T(t + 2, cur);

        __builtin_amdgcn_s_setprio(1);
#pragma unroll
        for (int i = 2; i < 4; ++i)
#pragma unroll
            for (int j = 0; j < 4; ++j)
                acc[i][j] = __builtin_amdgcn_mfma_f32_16x16x32_bf16(
                    af[i], bf[j], acc[i][j], 0, 0, 0);
        __builtin_amdgcn_s_setprio(0);

        if (t + 1 < NT) {
            if (t + 2 < NT) {
                asm volatile("s_waitcnt vmcnt(4)" ::: "memory");
            } else {
                asm volatile("s_waitcnt vmcnt(0)" ::: "memory");
            }
            __builtin_amdgcn_s_barrier();
        }
    }
#undef STAGE_T
#undef LDA_F
#undef LDB_F

    const int hi = lane >> 4;
    const int r = lane & 15;

    if (EPI == EPI_COMBINE) {
        // h -> parent hhhu slots via LDS panel, coalesced 128B bursts.
        __bf16* pan = &lds[0][0][0];  // [256][72]
        const int g0 = bn0 >> 2;
        float bz4[4];
#pragma unroll
        for (int g = 0; g < 4; ++g) bz4[g] = bias[bn0 + wc * 64 + g * 16 + r];
        const int G = g0 + wc * 16 + r;
#pragma unroll
        for (int i = 0; i < 4; ++i) {
#pragma unroll
            for (int reg = 0; reg < 4; ++reg) {
                const int lr = wr * 64 + i * 16 + hi * 4 + reg;
                const int gr = bm0 + lr;
                float z0 = acc[i][0][reg] + bz4[0];
                float z1 = acc[i][1][reg] + bz4[1];
                float z2 = acc[i][2][reg] + bz4[2];
                float z3 = acc[i][3][reg] + bz4[3];
                float mx = fmaxf(fmaxf(z0, z1), fmaxf(z2, z3));
                float e0 = __expf(z0 - mx), e1 = __expf(z1 - mx);
                float e2 = __expf(z2 - mx), e3 = __expf(z3 - mx);
                const __bf16* hrow = aux + (size_t)gr * ldaux + G;
                float hv = (e0 * (float)hrow[0] + e1 * (float)hrow[256] +
                            e2 * (float)hrow[512] + e3 * (float)hrow[768]) /
                           (e0 + e1 + e2 + e3);
                pan[lr * 72 + wc * 16 + r] = (__bf16)hv;
            }
        }
        __syncthreads();
        const int cbase = r0c + bm0;  // 256-aligned child row base
#pragma unroll
        for (int it = 0; it < 2; ++it) {
            const int unit = it * 1024 + tid;
            const int row = unit >> 3;
            const int c8 = (unit & 7) * 8;
            const int crow = cbase + row;
            bf16x8_t vv = *(const bf16x8_t*)&pan[row * 72 + c8];
            *(bf16x8_t*)((__bf16*)Cout + (size_t)(crow >> 1) * 1024 + 512 +
                         (crow & 1) * 256 + g0 + c8) = vv;
        }
        // Fused parent-u: one writer column-block per 128-parent range.
        if (bn0 == 0 && lev >= 1) {
            write_parent_u<1024, 128>(dataF, WuF, buF, (__bf16*)Cout,
                                      cbase >> 1, lev - 1, tid);
        }
    } else {  // EPI_SIGMUL
        __bf16* pan = &lds[0][0][0];  // [256][256]
        float bv[4];
#pragma unroll
        for (int j = 0; j < 4; ++j) bv[j] = bias[bn0 + wc * 64 + j * 16 + r];
#pragma unroll
        for (int j = 0; j < 4; ++j) {
            const int lc = wc * 64 + j * 16 + r;
            const int gc = bn0 + lc;
#pragma unroll
            for (int i = 0; i < 4; ++i) {
#pragma unroll
                for (int reg = 0; reg < 4; ++reg) {
                    const int lr = wr * 64 + i * 16 + hi * 4 + reg;
                    const int gr = bm0 + lr;
                    float v = acc[i][j][reg] + bv[j];
                    float s = 1.0f / (1.0f + __expf(-v));
                    v = s * (float)aux[(size_t)gr * ldaux + gc];
                    pan[lr * 256 + lc] = (__bf16)v;
                }
            }
        }
        __syncthreads();
#pragma unroll
        for (int it = 0; it < 8; ++it) {
            const int unit = it * 1024 + tid;
            const int row = unit >> 5;
            const int c8 = (unit & 31) * 8;
            bf16x8_t vv = *(const bf16x8_t*)&pan[row * 256 + c8];
            *(bf16x8_t*)((__bf16*)Cout + (size_t)(bm0 + row) * ldc + bn0 + c8) = vv;
        }
    }
}

// ---------------- 128x128-tile kernel (Wh + small levels) -------------------
// COMBINE: topar=1 -> write parent hhhu slots (+ fused parent-u on bn0==0);
// topar=0 -> compact (ldc).
template <int EPI>
__global__ __launch_bounds__(256) void gemm_mfma(
    const __bf16* __restrict__ A, int lda,
    const __bf16* __restrict__ W,
    const float* __restrict__ bias,
    const __bf16* __restrict__ aux, int ldaux,
    void* __restrict__ Cout, int ldc,
    int r0c, int topar,
    const float* __restrict__ dataF, const float* __restrict__ WuF,
    const float* __restrict__ buF, int lev,
    int K)
{
    __shared__ __bf16 As[128 * 32];
    __shared__ __bf16 Bs[128 * 32];
    const int tid = threadIdx.x;
    const int lane = tid & 63;
    const int w = tid >> 6;
    const int wr = w >> 1, wc = w & 1;

    const int nwg = gridDim.x * gridDim.y;
    const int hw = blockIdx.y * gridDim.x + blockIdx.x;
    const int wg = xcd_remap(hw, nwg);
    const int bm0 = (wg / gridDim.x) * 128;
    const int bn0 = (wg % gridDim.x) * 128;

    const int srow = lane >> 2;
    const int scol = (lane & 3) * 8;

    f32x4_t acc[4][4];
#pragma unroll
    for (int i = 0; i < 4; ++i)
#pragma unroll
        for (int j = 0; j < 4; ++j) acc[i][j] = (f32x4_t){0.f, 0.f, 0.f, 0.f};

    const int rA = lane & 15;
    const int kslot = (lane >> 4) * 8;

    for (int kk = 0; kk < K; kk += 32) {
        stage16(A + (size_t)(bm0 + w * 16 + srow) * lda + kk + scol,
                &As[(w * 16) * 32]);
        stage16(A + (size_t)(bm0 + 64 + w * 16 + srow) * lda + kk + scol,
                &As[(64 + w * 16) * 32]);
        stage16(W + (size_t)(bn0 + w * 16 + srow) * K + kk + scol,
                &Bs[(w * 16) * 32]);
        stage16(W + (size_t)(bn0 + 64 + w * 16 + srow) * K + kk + scol,
                &Bs[(64 + w * 16) * 32]);
        __syncthreads();

        bf16x8_t af[4], bfr[4];
#pragma unroll
        for (int i = 0; i < 4; ++i)
            af[i] = *(const bf16x8_t*)&As[(wr * 64 + i * 16 + rA) * 32 + kslot];
#pragma unroll
        for (int j = 0; j < 4; ++j)
            bfr[j] = *(const bf16x8_t*)&Bs[(wc * 64 + j * 16 + rA) * 32 + kslot];
#pragma unroll
        for (int i = 0; i < 4; ++i)
#pragma unroll
            for (int j = 0; j < 4; ++j)
                acc[i][j] = __builtin_amdgcn_mfma_f32_16x16x32_bf16(
                    af[i], bfr[j], acc[i][j], 0, 0, 0);
        __syncthreads();
    }

    if (EPI == EPI_COMBINE) {
        const int r = lane & 15;
        const int G = ((bn0 + wc * 64) >> 2) + r;
        float bz4[4];
#pragma unroll
        for (int g = 0; g < 4; ++g) bz4[g] = bias[bn0 + wc * 64 + g * 16 + r];
#pragma unroll
        for (int i = 0; i < 4; ++i) {
#pragma unroll
            for (int reg = 0; reg < 4; ++reg) {
                const int gr = bm0 + wr * 64 + i * 16 + (lane >> 4) * 4 + reg;
                float z0 = acc[i][0][reg] + bz4[0];
                float z1 = acc[i][1][reg] + bz4[1];
                float z2 = acc[i][2][reg] + bz4[2];
                float z3 = acc[i][3][reg] + bz4[3];
                float mx = fmaxf(fmaxf(z0, z1), fmaxf(z2, z3));
                float e0 = __expf(z0 - mx), e1 = __expf(z1 - mx);
                float e2 = __expf(z2 - mx), e3 = __expf(z3 - mx);
                const __bf16* hrow = aux + (size_t)gr * ldaux + G;
                float hv = (e0 * (float)hrow[0] + e1 * (float)hrow[256] +
                            e2 * (float)hrow[512] + e3 * (float)hrow[768]) /
                           (e0 + e1 + e2 + e3);
                if (topar) {
                    const int crow = r0c + gr;
                    ((__bf16*)Cout)[(size_t)(crow >> 1) * 1024 + 512 +
                                    (crow & 1) * 256 + G] = (__bf16)hv;
                } else {
                    ((__bf16*)Cout)[(size_t)gr * ldc + G] = (__bf16)hv;
                }
            }
        }
        if (topar && bn0 == 0 && lev >= 1) {
            write_parent_u<256, 64>(dataF, WuF, buF, (__bf16*)Cout,
                                    (r0c + bm0) >> 1, lev - 1, tid);
        }
    } else {
#pragma unroll
        for (int j = 0; j < 4; ++j) {
            const int gc = bn0 + wc * 64 + j * 16 + (lane & 15);
            const float bv = bias[gc];
#pragma unroll
            for (int i = 0; i < 4; ++i) {
#pragma unroll
                for (int reg = 0; reg < 4; ++reg) {
                    const int gr = bm0 + wr * 64 + i * 16 + (lane >> 4) * 4 + reg;
                    float v = acc[i][j][reg] + bv;
                    if (EPI == EPI_SIGMUL) {
                        float s = 1.0f / (1.0f + __expf(-v));
                        v = s * (float)aux[(size_t)gr * ldaux + gc];
                        ((__bf16*)Cout)[(size_t)gr * ldc + gc] = (__bf16)v;
                    } else {  // RELU
                        v = fmaxf(v, 0.0f);
                        ((__bf16*)Cout)[(size_t)gr * ldc + gc] = (__bf16)v;
                    }
                }
            }
        }
    }
}

// Wr/Wh -> bf16; Wz -> bf16 with softmax-group row permutation.
__global__ __launch_bounds__(256) void convert_weights(
    const float* __restrict__ Wr, const float* __restrict__ Wh,
    const float* __restrict__ Wz, const float* __restrict__ bz,
    __bf16* __restrict__ Wrb, __bf16* __restrict__ Whb,
    __bf16* __restrict__ Wzb, float* __restrict__ bzp)
{
    const int NR = 768 * 768, NH2 = 256 * 768, NZ = 1024 * 1024;
    const int idx0 = blockIdx.x * 256 + threadIdx.x;
    for (int i = idx0; i < NR + NH2 + NZ; i += gridDim.x * 256) {
        if (i < NR) Wrb[i] = (__bf16)Wr[i];
        else if (i < NR + NH2) Whb[i - NR] = (__bf16)Wh[i - NR];
        else {
            const int z = i - NR - NH2;
            const int p = z >> 10, k = z & 1023;
            const int o = ((p >> 4) & 3) * 256 + (p >> 6) * 16 + (p & 15);
            Wzb[z] = (__bf16)Wz[(size_t)o * 1024 + k];
        }
    }
    if (idx0 < 1024) {
        const int p = idx0;
        const int o = ((p >> 4) & 3) * 256 + (p >> 6) * 16 + (p & 15);
        bzp[p] = bz[o];
    }
}

// l==8 only: fill hhhu slice rows with [u | h_leaf_l | h_leaf_r].
__global__ __launch_bounds__(256) void build_leaf(
    const float* __restrict__ data, const float* __restrict__ Wu,
    const float* __restrict__ bu, __bf16* __restrict__ slice, int r0)
{
    const int blk = xcd_remap(blockIdx.x, gridDim.x);
    const int row = blk * 8 + (threadIdx.x >> 5);
    const int c0 = (threadIdx.x & 31) * 8;
    const int i = r0 + row;
    const int b = i >> 8;
    const int m = i & 255;

    float wv[8][8];
#pragma unroll
    for (int cc = 0; cc < 8; ++cc) {
        float4 w0 = *(const float4*)&Wu[(c0 + cc) * 8];
        float4 w1 = *(const float4*)&Wu[(c0 + cc) * 8 + 4];
        wv[cc][0] = w0.x; wv[cc][1] = w0.y; wv[cc][2] = w0.z; wv[cc][3] = w0.w;
        wv[cc][4] = w1.x; wv[cc][5] = w1.y; wv[cc][6] = w1.z; wv[cc][7] = w1.w;
    }
    float buv[8];
#pragma unroll
    for (int cc = 0; cc < 8; ++cc) buv[cc] = bu[c0 + cc];

    __bf16* rowp = slice + (size_t)row * 1024;
    {
        const float* dp = data + ((size_t)b * NN + 255 + m) * FF;
        float4 d0 = *(const float4*)dp, d1 = *(const float4*)(dp + 4);
        float dv[8] = {d0.x, d0.y, d0.z, d0.w, d1.x, d1.y, d1.z, d1.w};
        bf16x8_t o;
#pragma unroll
        for (int cc = 0; cc < 8; ++cc) {
            float acc = buv[cc];
#pragma unroll
            for (int f = 0; f < 8; ++f) acc += dv[f] * wv[cc][f];
            o[cc] = (__bf16)acc;
        }
        *(bf16x8_t*)&rowp[256 + c0] = o;
    }
    const float* dl = data + ((size_t)b * NN + 511 + 2 * m) * FF;
#pragma unroll
    for (int side = 0; side < 2; ++side) {
        const float* dp = dl + side * FF;
        float4 d0 = *(const float4*)dp, d1 = *(const float4*)(dp + 4);
        float dv[8] = {d0.x, d0.y, d0.z, d0.w, d1.x, d1.y, d1.z, d1.w};
        bf16x8_t o;
#pragma unroll
        for (int cc = 0; cc < 8; ++cc) {
            float acc = buv[cc];
#pragma unroll
            for (int f = 0; f < 8; ++f) acc += dv[f] * wv[cc][f];
            o[cc] = (__bf16)acc;
        }
        *(bf16x8_t*)&rowp[512 + side * 256 + c0] = o;
    }
}

__global__ __launch_bounds__(256) void final_kernel(
    const __bf16* __restrict__ hfin, const float* __restrict__ Wp,
    const float* __restrict__ bp, float* __restrict__ out)
{
    const int b = blockIdx.x;
    const int t = threadIdx.x;
    __shared__ float red[256];
    red[t] = (float)hfin[(size_t)b * HH + t] * Wp[t];
    __syncthreads();
    for (int s = 128; s > 0; s >>= 1) {
        if (t < s) red[t] += red[t + s];
        __syncthreads();
    }
    if (t == 0) out[b] = red[0] + bp[0];
}

extern "C" void kernel_launch(void* const* d_in, const int* in_sizes, int n_in,
                              void* d_out, int out_size, void* d_ws, size_t ws_size,
                              hipStream_t stream)
{
    const float* data = (const float*)d_in[0];
    const float* Wu = (const float*)d_in[1];
    const float* bu = (const float*)d_in[2];
    const float* Wr = (const float*)d_in[3];
    const float* br = (const float*)d_in[4];
    const float* Wh = (const float*)d_in[5];
    const float* bh = (const float*)d_in[6];
    const float* Wz = (const float*)d_in[7];
    const float* bz = (const float*)d_in[8];
    const float* Wp = (const float*)d_in[9];
    const float* bp = (const float*)d_in[10];
    float* out = (float*)d_out;

    const size_t CAP = 16384;
    char* w = (char*)d_ws;
    __bf16* hhhuA = (__bf16*)w; w += (size_t)65536 * 1024 * 2;  // 134.2 MB (l even)
    __bf16* hhhuB = (__bf16*)w; w += (size_t)32768 * 1024 * 2;  // 67.1 MB (l odd)
    __bf16* rh = (__bf16*)w;    w += CAP * 768 * 2;             // 25.2 MB
    __bf16* hRoot = (__bf16*)w; w += (size_t)256 * 256 * 2;
    __bf16* Wrb = (__bf16*)w;   w += (size_t)768 * 768 * 2;
    __bf16* Whb = (__bf16*)w;   w += (size_t)256 * 768 * 2;
    __bf16* Wzb = (__bf16*)w;   w += (size_t)1024 * 1024 * 2;
    float* bzp = (float*)w;     w += 1024 * 4;

    convert_weights<<<2048, 256, 0, stream>>>(Wr, Wh, Wz, bz, Wrb, Whb, Wzb, bzp);

    for (int l = DEPTH - 1; l >= 0; --l) {
        const size_t M = (size_t)BB << l;
        __bf16* cur = (l & 1) ? hhhuB : hhhuA;
        __bf16* par = (l == 0) ? hRoot : ((l & 1) ? hhhuA : hhhuB);
        const int topar = (l > 0);
        for (size_t r0 = 0; r0 < M; r0 += CAP) {
            const int R = (int)((M - r0 < CAP) ? (M - r0) : CAP);
            __bf16* slice = cur + (size_t)r0 * 1024;
            if (l == 8)
                build_leaf<<<R / 8, 256, 0, stream>>>(data, Wu, bu, slice, (int)r0);
            // l<8: u-slot was already written by level l+1's fused COMBINE.
            if (R >= 16384) {
                gemm256w<EPI_SIGMUL><<<dim3(3, R / 256), 1024, 0, stream>>>(
                    slice + 256, 1024, Wrb, br, slice + 256, 1024, rh, 768, 0,
                    nullptr, nullptr, nullptr, 0, 768);
            } else {
                gemm_mfma<EPI_SIGMUL><<<dim3(6, R / 128), 256, 0, stream>>>(
                    slice + 256, 1024, Wrb, br, slice + 256, 1024, rh, 768, 0, 0,
                    nullptr, nullptr, nullptr, 0, 768);
            }
            gemm_mfma<EPI_RELU><<<dim3(2, R / 128), 256, 0, stream>>>(
                rh, 768, Whb, bh, nullptr, 0, slice, 1024, 0, 0,
                nullptr, nullptr, nullptr, 0, 768);
            if (R >= 16384) {
                gemm256w<EPI_COMBINE><<<dim3(4, R / 256), 1024, 0, stream>>>(
                    slice, 1024, Wzb, bzp, slice, 1024, par, HH, (int)r0,
                    data, Wu, bu, l, 1024);
            } else {
                gemm_mfma<EPI_COMBINE><<<dim3(8, R / 128), 256, 0, stream>>>(
                    slice, 1024, Wzb, bzp, slice, 1024, par, HH, (int)r0, topar,
                    data, Wu, bu, l, 1024);
            }
        }
    }
    final_kernel<<<BB, 256, 0, stream>>>(hRoot, Wp, bp, out);
}